// Round 3
// baseline (438.091 us; speedup 1.0000x reference)
//
#include <hip/hip_runtime.h>

#define H 8
#define D 32
#define HD 256
#define NEG_SLOPE 0.2f

typedef __attribute__((ext_vector_type(8))) short bf8;
typedef __attribute__((ext_vector_type(4))) float f4;

// fp32 -> bf16 (round-to-nearest-even), integer path
__device__ __forceinline__ unsigned short f2b(float x) {
    unsigned u = __float_as_uint(x);
    unsigned r = (u + 0x7fffu + ((u >> 16) & 1u)) >> 16;
    return (unsigned short)r;
}

// prep: W transpose->bf16 | dst histogram | M_e (8x8).  (feat cvt removed:
// k_gemm now reads f32 feat directly.)
__global__ __launch_bounds__(256) void k_prep(
        const float* __restrict__ W, unsigned short* __restrict__ Wtb,
        const float* __restrict__ W_e, const float* __restrict__ attn_e,
        float* __restrict__ M, const int* __restrict__ dst, int* __restrict__ cnt,
        int E, int bh) {
    const int b = blockIdx.x, t = threadIdx.x;
    if (b < HD) {                          // ---- W transpose ----
        Wtb[b * HD + t] = f2b(W[t * HD + b]);
    } else if (b < HD + bh) {              // ---- histogram ----
        int e = (b - HD) * 256 + t;
        if (e < E) atomicAdd(&cnt[dst[e]], 1);
    } else {                               // ---- M_e ----
        if (t < 64) {
            int k = t >> 3, hh = t & 7;
            float acc = 0.f;
            for (int d = 0; d < D; ++d)
                acc = fmaf(W_e[k * HD + hh * D + d], attn_e[hh * D + d], acc);
            M[k * 8 + hh] = acc;
        }
    }
}

// single-block chained exclusive scan over cnt[0..N): offs, cur, offs[N]=E.
// Replaces the 3-kernel scan (fewer dispatches in the serial chain).
__global__ __launch_bounds__(1024) void k_scan(const int* __restrict__ cnt,
                                               int* __restrict__ offs,
                                               int* __restrict__ cur, int N, int E) {
    __shared__ int wtot[16], wbase[16], ttot;
    const int t = threadIdx.x, wid = t >> 6, lane = t & 63;
    int base = 0;
    for (int i0 = 0; i0 < N; i0 += 1024) {
        const int i = i0 + t;
        const int v = (i < N) ? cnt[i] : 0;
        int x = v;
#pragma unroll
        for (int off = 1; off < 64; off <<= 1) {
            int y = __shfl_up(x, off, 64);
            if (lane >= off) x += y;
        }
        __syncthreads();                 // wtot/wbase/ttot free from prev iter
        if (lane == 63) wtot[wid] = x;
        __syncthreads();
        if (t < 16) {
            int w = wtot[t], xs = w;
#pragma unroll
            for (int off = 1; off < 16; off <<= 1) {
                int y = __shfl_up(xs, off, 64);
                if (t >= off) xs += y;
            }
            wbase[t] = xs - w;
            if (t == 15) ttot = xs;
        }
        __syncthreads();
        if (i < N) {
            const int o = base + wbase[wid] + (x - v);
            offs[i] = o;
            cur[i] = o;
        }
        base += ttot;
    }
    if (t == 0) offs[N] = E;
}

// LDS-free MFMA GEMM: each wave owns a 16-row x 256-col strip.
// A now read DIRECTLY from f32 feat (cvt to bf16 in-register, same f2b RNE
// as the old featb pass -> bit-identical h).  B fragments from bf16 Wtb.
// hb is NODE-major [N][256] (k_node reads full 512B rows).
__global__ __launch_bounds__(256) void k_gemm(
        const float* __restrict__ feat, const unsigned short* __restrict__ Wtb,
        const float* __restrict__ attn_l, const float* __restrict__ attn_r,
        unsigned short* __restrict__ hb, float* __restrict__ el, float* __restrict__ er,
        int N) {
    const int t = threadIdx.x;
    const int l = t & 63, wv = t >> 6;
    const int row0 = (blockIdx.x * 4 + wv) * 16;   // N % 16 == 0: no row guards
    if (row0 >= N) return;
    const int m = l & 15, q = l >> 4;

    // preload all 8 A-fragments (row = row0+m), f32 -> bf16 in-register
    bf8 afr[8];
    const float* arow = feat + (size_t)(row0 + m) * HD + q * 8;
#pragma unroll
    for (int kc = 0; kc < 8; ++kc) {
        const float4 f0 = *(const float4*)(arow + kc * 32);
        const float4 f1 = *(const float4*)(arow + kc * 32 + 4);
        bf8 a;
        a[0] = (short)f2b(f0.x); a[1] = (short)f2b(f0.y);
        a[2] = (short)f2b(f0.z); a[3] = (short)f2b(f0.w);
        a[4] = (short)f2b(f1.x); a[5] = (short)f2b(f1.y);
        a[6] = (short)f2b(f1.z); a[7] = (short)f2b(f1.w);
        afr[kc] = a;
    }

    f4 acc[16];
#pragma unroll
    for (int nt = 0; nt < 16; ++nt) acc[nt] = (f4){0.f, 0.f, 0.f, 0.f};

    const unsigned short* bcol = Wtb + (size_t)m * HD + q * 8;   // col = nt*16+m
#pragma unroll
    for (int nt = 0; nt < 16; ++nt) {
        const unsigned short* bp = bcol + (size_t)nt * 16 * HD;
#pragma unroll
        for (int kc = 0; kc < 8; ++kc) {
            const bf8 b = *(const bf8*)(bp + kc * 32);
            acc[nt] = __builtin_amdgcn_mfma_f32_16x16x32_bf16(afr[kc], b, acc[nt], 0, 0, 0);
        }
    }

    // epilogue: C/D layout col = l&15, row = q*4+reg.  Store hb; full el/er
    // per row via width-16 butterflies.
#pragma unroll
    for (int h = 0; h < H; ++h) {
        float elp[4] = {0.f, 0.f, 0.f, 0.f};
        float erp[4] = {0.f, 0.f, 0.f, 0.f};
#pragma unroll
        for (int s = 0; s < 2; ++s) {
            const int nt = h * 2 + s;
            const int c = nt * 16 + m;
            const float alc = attn_l[c];
            const float arc = attn_r[c];
#pragma unroll
            for (int reg = 0; reg < 4; ++reg) {
                const float v = acc[nt][reg];
                hb[(size_t)(row0 + q * 4 + reg) * HD + c] = f2b(v);
                elp[reg] = fmaf(v, alc, elp[reg]);
                erp[reg] = fmaf(v, arc, erp[reg]);
            }
        }
#pragma unroll
        for (int reg = 0; reg < 4; ++reg) {
#pragma unroll
            for (int off = 1; off < 16; off <<= 1) {
                elp[reg] += __shfl_xor(elp[reg], off, 16);
                erp[reg] += __shfl_xor(erp[reg], off, 16);
            }
        }
        if (m == 0) {
#pragma unroll
            for (int reg = 0; reg < 4; ++reg) {
                el[(row0 + q * 4 + reg) * H + h] = elp[reg];
                er[(row0 + q * 4 + reg) * H + h] = erp[reg];
            }
        }
    }
}

// tiny CSR scatter: pair_csr[slot] = (src, edge_id).
__global__ void k_scat(const int* __restrict__ src, const int* __restrict__ dst,
                       int* __restrict__ cur, uint2* __restrict__ pair, int E) {
    int e = blockIdx.x * blockDim.x + threadIdx.x;
    if (e >= E) return;
    int de = dst[e];
    int p = atomicAdd(&cur[de], 1);
    pair[p] = make_uint2((unsigned)src[e], (unsigned)e);
}

// aggregation v3: ONE WAVE per node.  Zero LDS, zero barriers; pairs live in
// registers (lane j owns edge j of the 64-edge tile); p shared via shfl with
// statically-indexed pv[s] (no scratch).  Agg unrolled 8-deep per s-block ->
// 8 independent 512B row gathers in flight per wave.
__global__ __launch_bounds__(256) void k_node(
        const int* __restrict__ offs, const uint2* __restrict__ pair,
        const float* __restrict__ edge_emb, const float* __restrict__ el,
        const float* __restrict__ er, const float* __restrict__ M,
        const unsigned short* __restrict__ hb, const float* __restrict__ bias,
        float* __restrict__ out, int N) {
    const int t = threadIdx.x;
    const int lane = t & 63;
    const int v = blockIdx.x * 4 + (t >> 6);
    if (v >= N) return;
    const int hh = lane & 7;        // p-phase: head
    const int hq = lane >> 3;       // agg: head of this lane's 4 cols
    const int cb = lane * 4;        // agg: col base (uint2 = 4 bf16 cols)
    const int s0 = offs[v];
    const int deg = offs[v + 1] - s0;

    float Mreg[8];
#pragma unroll
    for (int k = 0; k < 8; ++k) Mreg[k] = M[k * 8 + hh];
    const float erv = er[(size_t)v * 8 + hh];
    const unsigned short* hbc = hb + cb;

    float a0 = 0.f, a1 = 0.f, a2 = 0.f, a3 = 0.f, psum = 0.f;

    for (int j0 = 0; j0 < deg; j0 += 64) {
        const int nj = min(64, deg - j0);
        uint2 prl = make_uint2(0u, 0u);
        if (lane < nj) prl = pair[s0 + j0 + lane];

        // ---- p-phase: 8 edges x 8 heads per sub-step ----
        float pv[8];
#pragma unroll
        for (int s = 0; s < 8; ++s) {
            pv[s] = 0.f;
            if (s * 8 < nj) {                       // wave-uniform
                const int j = s * 8 + (lane >> 3);
                const unsigned sx = __shfl(prl.x, j, 64);
                const unsigned ex = __shfl(prl.y, j, 64);
                const float eev = edge_emb[(size_t)ex * 8 + hh];
                float lg = el[(size_t)sx * 8 + hh] + erv;
#pragma unroll
                for (int k = 0; k < 8; ++k)
                    lg = fmaf(__shfl(eev, k, 8), Mreg[k], lg);
                lg = (lg >= 0.f) ? lg : NEG_SLOPE * lg;
                if (j < nj) { pv[s] = __expf(lg); psum += pv[s]; }
            }
        }

        // ---- aggregation: a += p * h[src] ----
#pragma unroll
        for (int s = 0; s < 8; ++s) {
            if (s * 8 >= nj) break;                 // wave-uniform
#pragma unroll
            for (int jj = 0; jj < 8; ++jj) {
                const int j = s * 8 + jj;
                if (j >= nj) break;                 // wave-uniform
                const unsigned sx = __shfl(prl.x, j, 64);
                const float pj = __shfl(pv[s], jj * 8 + hq, 64);
                const uint2 w = *(const uint2*)(hbc + (size_t)sx * HD);
                a0 = fmaf(pj, __uint_as_float(w.x << 16), a0);
                a1 = fmaf(pj, __uint_as_float(w.x & 0xffff0000u), a1);
                a2 = fmaf(pj, __uint_as_float(w.y << 16), a2);
                a3 = fmaf(pj, __uint_as_float(w.y & 0xffff0000u), a3);
            }
        }
    }

    // per-head sum of p (lanes with equal lane&7 hold partials), deferred norm
    psum += __shfl_xor(psum, 8, 64);
    psum += __shfl_xor(psum, 16, 64);
    psum += __shfl_xor(psum, 32, 64);
    const float rs = 1.f / (__shfl(psum, hq, 8) + 1e-9f);
    const float4 b4 = *(const float4*)&bias[cb];
    *(float4*)&out[(size_t)v * HD + cb] =
        make_float4(fmaf(a0, rs, b4.x), fmaf(a1, rs, b4.y),
                    fmaf(a2, rs, b4.z), fmaf(a3, rs, b4.w));
}

extern "C" void kernel_launch(void* const* d_in, const int* in_sizes, int n_in,
                              void* d_out, int out_size, void* d_ws, size_t ws_size,
                              hipStream_t stream) {
    const float* feat     = (const float*)d_in[0];
    const float* edge_emb = (const float*)d_in[1];
    const int*   src      = (const int*)d_in[2];
    const int*   dst      = (const int*)d_in[3];
    const float* W_src    = (const float*)d_in[4];
    const float* W_e      = (const float*)d_in[5];
    const float* attn_l   = (const float*)d_in[6];
    const float* attn_r   = (const float*)d_in[7];
    const float* attn_e   = (const float*)d_in[8];
    const float* bias     = (const float*)d_in[9];
    float* out = (float*)d_out;

    const int N = in_sizes[0] / HD;
    const int E = in_sizes[2];

    char* ws = (char*)d_ws;
    unsigned short* hb = (unsigned short*)ws; ws += (size_t)N * HD * 2;   // bf16 h
    uint2* pair = (uint2*)ws; ws += (size_t)E * 8;
    float* el   = (float*)ws; ws += (size_t)N * H * 4;   // fully written by k_gemm
    float* er   = (float*)ws; ws += (size_t)N * H * 4;   // fully written by k_gemm
    int*   cnt  = (int*)ws;   ws += (size_t)N * 4;
    int* offs    = (int*)ws; ws += (size_t)(N + 1) * 4;
    int* cur     = (int*)ws; ws += (size_t)N * 4;
    unsigned short* Wtb = (unsigned short*)ws; ws += (size_t)HD * HD * 2;
    float* M   = (float*)ws; ws += 256;

    const int bh = (E + 255) / 256;

    hipMemsetAsync(cnt, 0, (size_t)N * 4, stream);
    k_prep <<<HD + bh + 1, 256, 0, stream>>>(W_src, Wtb, W_e, attn_e, M, dst, cnt, E, bh);
    k_scan <<<1, 1024, 0, stream>>>(cnt, offs, cur, N, E);
    {
        const int nwaves = (N + 15) / 16;                  // 3125
        k_gemm <<<(nwaves + 3) / 4, 256, 0, stream>>>(feat, Wtb, attn_l, attn_r,
                                                      hb, el, er, N);
    }
    k_scat <<<(E + 255) / 256, 256, 0, stream>>>(src, dst, cur, pair, E);
    k_node <<<(N + 3) / 4, 256, 0, stream>>>(offs, pair, edge_emb, el, er, M,
                                             hb, bias, out, N);
}

// Round 4
// 379.048 us; speedup vs baseline: 1.1558x; 1.1558x over previous
//
#include <hip/hip_runtime.h>

#define H 8
#define D 32
#define HD 256
#define NEG_SLOPE 0.2f
#define SCB 1024

typedef __attribute__((ext_vector_type(8))) short bf8;
typedef __attribute__((ext_vector_type(4))) float f4;

// fp32 -> bf16 (round-to-nearest-even), integer path
__device__ __forceinline__ unsigned short f2b(float x) {
    unsigned u = __float_as_uint(x);
    unsigned r = (u + 0x7fffu + ((u >> 16) & 1u)) >> 16;
    return (unsigned short)r;
}

// fused prep: feat->bf16 cvt | W transpose->bf16 | dst histogram | M_e (8x8)
__global__ __launch_bounds__(256) void k_prep(
        const float* __restrict__ feat, unsigned short* __restrict__ featb, int n8,
        const float* __restrict__ W, unsigned short* __restrict__ Wtb,
        const float* __restrict__ W_e, const float* __restrict__ attn_e,
        float* __restrict__ M, const int* __restrict__ dst, int* __restrict__ cnt,
        int E, int bc, int bh) {
    const int b = blockIdx.x, t = threadIdx.x;
    if (b < bc) {                          // ---- cvt ----
        int idx = b * 256 + t;
        if (idx >= n8) return;
        const float4* f = (const float4*)feat;
        float4 a = f[idx * 2], v = f[idx * 2 + 1];
        uint4 o;
        o.x = f2b(a.x) | ((unsigned)f2b(a.y) << 16);
        o.y = f2b(a.z) | ((unsigned)f2b(a.w) << 16);
        o.z = f2b(v.x) | ((unsigned)f2b(v.y) << 16);
        o.w = f2b(v.z) | ((unsigned)f2b(v.w) << 16);
        ((uint4*)featb)[idx] = o;
    } else if (b < bc + HD) {              // ---- W transpose ----
        int n = b - bc;
        Wtb[n * HD + t] = f2b(W[t * HD + n]);
    } else if (b < bc + HD + bh) {         // ---- histogram ----
        int e = (b - bc - HD) * 256 + t;
        if (e < E) atomicAdd(&cnt[dst[e]], 1);
    } else {                               // ---- M_e ----
        if (t < 64) {
            int k = t >> 3, hh = t & 7;
            float acc = 0.f;
            for (int d = 0; d < D; ++d)
                acc = fmaf(W_e[k * HD + hh * D + d], attn_e[hh * D + d], acc);
            M[k * 8 + hh] = acc;
        }
    }
}

// parallel exclusive scan, step 1: block-local scan + block totals
__global__ __launch_bounds__(1024) void k_scan1(const int* __restrict__ cnt,
                                                int* __restrict__ offs,
                                                int* __restrict__ btot, int N) {
    __shared__ int wtot[16], wbase[16];
    const int t = threadIdx.x, wid = t >> 6, lane = t & 63;
    int i = blockIdx.x * SCB + t;
    int v = (i < N) ? cnt[i] : 0;
    int x = v;
#pragma unroll
    for (int off = 1; off < 64; off <<= 1) {
        int y = __shfl_up(x, off, 64);
        if (lane >= off) x += y;
    }
    if (lane == 63) wtot[wid] = x;
    __syncthreads();
    if (t < 16) {
        int w = wtot[t], xs = w;
#pragma unroll
        for (int off = 1; off < 16; off <<= 1) {
            int y = __shfl_up(xs, off, 64);
            if (t >= off) xs += y;
        }
        wbase[t] = xs - w;
        if (t == 15) btot[blockIdx.x] = xs;
    }
    __syncthreads();
    if (i < N) offs[i] = wbase[wid] + (x - v);
}

// step 2 (fused scan2+scan3): wave 0 re-scans the <=64 block totals, then the
// whole block adds its base.  One dispatch instead of two.
__global__ __launch_bounds__(1024) void k_scan3(int* __restrict__ offs,
                                                const int* __restrict__ btot,
                                                int* __restrict__ cur,
                                                int N, int E, int nb) {
    __shared__ int bb;
    const int t = threadIdx.x;
    if (t < 64) {
        int vv = (t < nb) ? btot[t] : 0;
        int x = vv;
#pragma unroll
        for (int off = 1; off < 64; off <<= 1) {
            int y = __shfl_up(x, off, 64);
            if (t >= off) x += y;
        }
        if (t == blockIdx.x) bb = x - vv;   // exclusive base for this block
    }
    __syncthreads();
    const int i = blockIdx.x * SCB + t;
    if (i < N) {
        const int o = offs[i] + bb;
        offs[i] = o;
        cur[i] = o;
    }
    if (i == 0) offs[N] = E;
}

// LDS-free MFMA GEMM: each wave owns a 16-row x 256-col strip.
// A/B fragments loaded directly from global in MFMA lane layout
// (lane l: row/col = l&15, k = kc*32 + (l>>4)*8, 16B contiguous).
// No barriers, no atomics; wave computes complete el/er rows.
// hb is NODE-major [N][256] (k_node reads full 512B rows).
__global__ __launch_bounds__(256) void k_gemm(
        const unsigned short* __restrict__ featb, const unsigned short* __restrict__ Wtb,
        const float* __restrict__ attn_l, const float* __restrict__ attn_r,
        unsigned short* __restrict__ hb, float* __restrict__ el, float* __restrict__ er,
        int N) {
    const int t = threadIdx.x;
    const int l = t & 63, wv = t >> 6;
    const int row0 = (blockIdx.x * 4 + wv) * 16;   // N % 16 == 0: no row guards
    if (row0 >= N) return;
    const int m = l & 15, q = l >> 4;

    // preload all 8 A-fragments (row = row0+m)
    bf8 afr[8];
    const unsigned short* arow = featb + (size_t)(row0 + m) * HD + q * 8;
#pragma unroll
    for (int kc = 0; kc < 8; ++kc)
        afr[kc] = *(const bf8*)(arow + kc * 32);

    f4 acc[16];
#pragma unroll
    for (int nt = 0; nt < 16; ++nt) acc[nt] = (f4){0.f, 0.f, 0.f, 0.f};

    const unsigned short* bcol = Wtb + (size_t)m * HD + q * 8;   // col = nt*16+m
#pragma unroll
    for (int nt = 0; nt < 16; ++nt) {
        const unsigned short* bp = bcol + (size_t)nt * 16 * HD;
#pragma unroll
        for (int kc = 0; kc < 8; ++kc) {
            const bf8 b = *(const bf8*)(bp + kc * 32);
            acc[nt] = __builtin_amdgcn_mfma_f32_16x16x32_bf16(afr[kc], b, acc[nt], 0, 0, 0);
        }
    }

    // epilogue: C/D layout col = l&15, row = q*4+reg.  Store hb; full el/er
    // per row via width-16 butterflies.
#pragma unroll
    for (int h = 0; h < H; ++h) {
        float elp[4] = {0.f, 0.f, 0.f, 0.f};
        float erp[4] = {0.f, 0.f, 0.f, 0.f};
#pragma unroll
        for (int s = 0; s < 2; ++s) {
            const int nt = h * 2 + s;
            const int c = nt * 16 + m;
            const float alc = attn_l[c];
            const float arc = attn_r[c];
#pragma unroll
            for (int reg = 0; reg < 4; ++reg) {
                const float v = acc[nt][reg];
                hb[(size_t)(row0 + q * 4 + reg) * HD + c] = f2b(v);
                elp[reg] = fmaf(v, alc, elp[reg]);
                erp[reg] = fmaf(v, arc, erp[reg]);
            }
        }
#pragma unroll
        for (int reg = 0; reg < 4; ++reg) {
#pragma unroll
            for (int off = 1; off < 16; off <<= 1) {
                elp[reg] += __shfl_xor(elp[reg], off, 16);
                erp[reg] += __shfl_xor(erp[reg], off, 16);
            }
        }
        if (m == 0) {
#pragma unroll
            for (int reg = 0; reg < 4; ++reg) {
                el[(row0 + q * 4 + reg) * H + h] = elp[reg];
                er[(row0 + q * 4 + reg) * H + h] = erp[reg];
            }
        }
    }
}

// tiny CSR scatter: pair_csr[slot] = (src, edge_id).
__global__ void k_scat(const int* __restrict__ src, const int* __restrict__ dst,
                       int* __restrict__ cur, uint2* __restrict__ pair, int E) {
    int e = blockIdx.x * blockDim.x + threadIdx.x;
    if (e >= E) return;
    int de = dst[e];
    int p = atomicAdd(&cur[de], 1);
    pair[p] = make_uint2((unsigned)src[e], (unsigned)e);
}

// aggregation v3: ONE WAVE per node, zero LDS/barriers.  Dual-edge gather:
// lane = (half=lane>>5, sl=lane&31); each lane reads uint4 (8 cols, 16B), so
// one load instruction fetches TWO full 512B h-rows (half=0 -> edge j,
// half=1 -> edge j+1).  Halves merged at the end via shfl_xor(32).
__global__ __launch_bounds__(256) void k_node(
        const int* __restrict__ offs, const uint2* __restrict__ pair,
        const float* __restrict__ edge_emb, const float* __restrict__ el,
        const float* __restrict__ er, const float* __restrict__ M,
        const unsigned short* __restrict__ hb, const float* __restrict__ bias,
        float* __restrict__ out, int N) {
    const int t = threadIdx.x;
    const int lane = t & 63;
    const int v = blockIdx.x * 4 + (t >> 6);
    if (v >= N) return;
    const int hh = lane & 7;        // p-phase: head
    const int sl = lane & 31;       // col-chunk slot (8 cols = 16B)
    const int half = lane >> 5;     // edge parity
    const int cb = sl * 8;
    const int hq = sl >> 2;         // head of this chunk
    const int s0 = offs[v];
    const int deg = offs[v + 1] - s0;

    float Mreg[8];
#pragma unroll
    for (int k = 0; k < 8; ++k) Mreg[k] = M[k * 8 + hh];
    const float erv = er[(size_t)v * 8 + hh];
    const unsigned short* hbc = hb + cb;

    float a[8];
#pragma unroll
    for (int i = 0; i < 8; ++i) a[i] = 0.f;
    float psum = 0.f;

    for (int j0 = 0; j0 < deg; j0 += 64) {
        const int nj = min(64, deg - j0);
        uint2 prl = make_uint2(0u, 0u);
        if (lane < nj) prl = pair[s0 + j0 + lane];

        // ---- p-phase: 8 edges x 8 heads per sub-step (lane = jj*8+hh) ----
        float pv[8];
#pragma unroll
        for (int s = 0; s < 8; ++s) {
            pv[s] = 0.f;
            if (s * 8 < nj) {                       // wave-uniform
                const int j = s * 8 + (lane >> 3);
                const unsigned sx = __shfl(prl.x, j, 64);
                const unsigned ex = __shfl(prl.y, j, 64);
                const float eev = edge_emb[(size_t)ex * 8 + hh];
                float lg = el[(size_t)sx * 8 + hh] + erv;
#pragma unroll
                for (int k = 0; k < 8; ++k)
                    lg = fmaf(__shfl(eev, k, 8), Mreg[k], lg);
                lg = (lg >= 0.f) ? lg : NEG_SLOPE * lg;
                if (j < nj) { pv[s] = __expf(lg); psum += pv[s]; }
            }
        }

        // ---- aggregation: 2 edges per load instruction ----
#pragma unroll
        for (int s = 0; s < 8; ++s) {
            if (s * 8 >= nj) break;                 // wave-uniform
#pragma unroll
            for (int u = 0; u < 4; ++u) {
                if (s * 8 + 2 * u >= nj) break;     // wave-uniform
                const int jj = 2 * u + half;
                const unsigned sx = __shfl(prl.x, s * 8 + jj, 64);
                const float pj = __shfl(pv[s], jj * 8 + hq, 64);  // 0 if j>=nj
                const uint4 w = *(const uint4*)(hbc + (size_t)sx * HD);
                a[0] = fmaf(pj, __uint_as_float(w.x << 16), a[0]);
                a[1] = fmaf(pj, __uint_as_float(w.x & 0xffff0000u), a[1]);
                a[2] = fmaf(pj, __uint_as_float(w.y << 16), a[2]);
                a[3] = fmaf(pj, __uint_as_float(w.y & 0xffff0000u), a[3]);
                a[4] = fmaf(pj, __uint_as_float(w.z << 16), a[4]);
                a[5] = fmaf(pj, __uint_as_float(w.z & 0xffff0000u), a[5]);
                a[6] = fmaf(pj, __uint_as_float(w.w << 16), a[6]);
                a[7] = fmaf(pj, __uint_as_float(w.w & 0xffff0000u), a[7]);
            }
        }
    }

    // merge edge-parity halves (same cols, disjoint edge subsets)
#pragma unroll
    for (int i = 0; i < 8; ++i) a[i] += __shfl_xor(a[i], 32, 64);

    // per-head sum of p, deferred normalization
    psum += __shfl_xor(psum, 8, 64);
    psum += __shfl_xor(psum, 16, 64);
    psum += __shfl_xor(psum, 32, 64);
    const float rs = 1.f / (__shfl(psum, hq, 8) + 1e-9f);
    if (half == 0) {
        const float4 b0 = *(const float4*)&bias[cb];
        const float4 b1 = *(const float4*)&bias[cb + 4];
        *(float4*)&out[(size_t)v * HD + cb] =
            make_float4(fmaf(a[0], rs, b0.x), fmaf(a[1], rs, b0.y),
                        fmaf(a[2], rs, b0.z), fmaf(a[3], rs, b0.w));
        *(float4*)&out[(size_t)v * HD + cb + 4] =
            make_float4(fmaf(a[4], rs, b1.x), fmaf(a[5], rs, b1.y),
                        fmaf(a[6], rs, b1.z), fmaf(a[7], rs, b1.w));
    }
}

extern "C" void kernel_launch(void* const* d_in, const int* in_sizes, int n_in,
                              void* d_out, int out_size, void* d_ws, size_t ws_size,
                              hipStream_t stream) {
    const float* feat     = (const float*)d_in[0];
    const float* edge_emb = (const float*)d_in[1];
    const int*   src      = (const int*)d_in[2];
    const int*   dst      = (const int*)d_in[3];
    const float* W_src    = (const float*)d_in[4];
    const float* W_e      = (const float*)d_in[5];
    const float* attn_l   = (const float*)d_in[6];
    const float* attn_r   = (const float*)d_in[7];
    const float* attn_e   = (const float*)d_in[8];
    const float* bias     = (const float*)d_in[9];
    float* out = (float*)d_out;

    const int N = in_sizes[0] / HD;
    const int E = in_sizes[2];

    char* ws = (char*)d_ws;
    unsigned short* hb = (unsigned short*)ws; ws += (size_t)N * HD * 2;   // bf16 h
    // featb (dead after k_gemm) aliases pair_csr (written after by k_scat)
    char* flog = ws;
    size_t sz_featb = (size_t)N * HD * 2;
    size_t sz_pair  = (size_t)E * 8;
    ws += (sz_featb > sz_pair ? sz_featb : sz_pair);
    unsigned short* featb = (unsigned short*)flog;
    uint2*          pair  = (uint2*)flog;
    float* el   = (float*)ws; ws += (size_t)N * H * 4;   // fully written by k_gemm
    float* er   = (float*)ws; ws += (size_t)N * H * 4;   // fully written by k_gemm
    int*   cnt  = (int*)ws;   ws += (size_t)N * 4;
    int* offs    = (int*)ws; ws += (size_t)(N + 1) * 4;
    int* cur     = (int*)ws; ws += (size_t)N * 4;
    unsigned short* Wtb = (unsigned short*)ws; ws += (size_t)HD * HD * 2;
    int* btot  = (int*)ws; ws += 64 * 4;
    float* M   = (float*)ws; ws += 256;

    const int n8  = N * HD / 8;
    const int bc  = (n8 + 255) / 256;
    const int bh  = (E + 255) / 256;
    const int nsb = (N + SCB - 1) / SCB;   // <= 64

    hipMemsetAsync(cnt, 0, (size_t)N * 4, stream);
    k_prep  <<<bc + HD + bh + 1, 256, 0, stream>>>(feat, featb, n8, W_src, Wtb,
                                                   W_e, attn_e, M, dst, cnt, E, bc, bh);
    k_scan1 <<<nsb, SCB, 0, stream>>>(cnt, offs, btot, N);
    k_scan3 <<<nsb, SCB, 0, stream>>>(offs, btot, cur, N, E, nsb);
    {
        const int nwaves = (N + 15) / 16;                  // 3125
        k_gemm <<<(nwaves + 3) / 4, 256, 0, stream>>>(featb, Wtb, attn_l, attn_r,
                                                      hb, el, er, N);
    }
    // k_scat AFTER k_gemm: pair aliases featb (dead once k_gemm finishes)
    k_scat  <<<(E + 255) / 256, 256, 0, stream>>>(src, dst, cur, pair, E);
    k_node  <<<(N + 3) / 4, 256, 0, stream>>>(offs, pair, edge_emb, el, er, M,
                                              hb, bias, out, N);
}

// Round 5
// 334.892 us; speedup vs baseline: 1.3082x; 1.1319x over previous
//
#include <hip/hip_runtime.h>

#define H 8
#define D 32
#define HD 256
#define NEG_SLOPE 0.2f
#define SCB 1024

typedef __attribute__((ext_vector_type(8))) short bf8;
typedef __attribute__((ext_vector_type(4))) float f4;

// fp32 -> bf16 (round-to-nearest-even), integer path
__device__ __forceinline__ unsigned short f2b(float x) {
    unsigned u = __float_as_uint(x);
    unsigned r = (u + 0x7fffu + ((u >> 16) & 1u)) >> 16;
    return (unsigned short)r;
}

// prep: W transpose->bf16 | dst histogram (+per-edge ordinal) | M_e (8x8).
// (feat cvt removed: k_fuse gemm reads f32 feat directly.)
__global__ __launch_bounds__(256) void k_prep(
        const float* __restrict__ W, unsigned short* __restrict__ Wtb,
        const float* __restrict__ W_e, const float* __restrict__ attn_e,
        float* __restrict__ M, const int* __restrict__ dst, int* __restrict__ cnt,
        int* __restrict__ ord, int E, int bh) {
    const int b = blockIdx.x, t = threadIdx.x;
    if (b < HD) {                          // ---- W transpose ----
        Wtb[b * HD + t] = f2b(W[t * HD + b]);
    } else if (b < HD + bh) {              // ---- histogram + ordinal ----
        int e = (b - HD) * 256 + t;
        if (e < E) ord[e] = atomicAdd(&cnt[dst[e]], 1);
    } else {                               // ---- M_e ----
        if (t < 64) {
            int k = t >> 3, hh = t & 7;
            float acc = 0.f;
            for (int d = 0; d < D; ++d)
                acc = fmaf(W_e[k * HD + hh * D + d], attn_e[hh * D + d], acc);
            M[k * 8 + hh] = acc;
        }
    }
}

// parallel exclusive scan, step 1: block-local scan + block totals
__global__ __launch_bounds__(1024) void k_scan1(const int* __restrict__ cnt,
                                                int* __restrict__ offs,
                                                int* __restrict__ btot, int N) {
    __shared__ int wtot[16], wbase[16];
    const int t = threadIdx.x, wid = t >> 6, lane = t & 63;
    int i = blockIdx.x * SCB + t;
    int v = (i < N) ? cnt[i] : 0;
    int x = v;
#pragma unroll
    for (int off = 1; off < 64; off <<= 1) {
        int y = __shfl_up(x, off, 64);
        if (lane >= off) x += y;
    }
    if (lane == 63) wtot[wid] = x;
    __syncthreads();
    if (t < 16) {
        int w = wtot[t], xs = w;
#pragma unroll
        for (int off = 1; off < 16; off <<= 1) {
            int y = __shfl_up(xs, off, 64);
            if (t >= off) xs += y;
        }
        wbase[t] = xs - w;
        if (t == 15) btot[blockIdx.x] = xs;
    }
    __syncthreads();
    if (i < N) offs[i] = wbase[wid] + (x - v);
}

// step 2 (fused scan2+scan3): wave 0 re-scans the <=64 block totals, then the
// whole block adds its base.  (cur eliminated: scat uses offs+ord.)
__global__ __launch_bounds__(1024) void k_scan3(int* __restrict__ offs,
                                                const int* __restrict__ btot,
                                                int N, int E, int nb) {
    __shared__ int bb;
    const int t = threadIdx.x;
    if (t < 64) {
        int vv = (t < nb) ? btot[t] : 0;
        int x = vv;
#pragma unroll
        for (int off = 1; off < 64; off <<= 1) {
            int y = __shfl_up(x, off, 64);
            if (t >= off) x += y;
        }
        if (t == blockIdx.x) bb = x - vv;   // exclusive base for this block
    }
    __syncthreads();
    const int i = blockIdx.x * SCB + t;
    if (i < N) offs[i] += bb;
    if (i == 0) offs[N] = E;
}

// fused dispatch: [0,bg) = LDS-free MFMA GEMM (f32 A, cvt in-register);
// [bg,bg+bs) = atomic-free CSR scatter (slot = offs[dst]+ord).  The scatter's
// latency-bound random 8B writes overlap the GEMM's MFMA/VMEM work.
__global__ __launch_bounds__(256) void k_fuse(
        const float* __restrict__ feat, const unsigned short* __restrict__ Wtb,
        const float* __restrict__ attn_l, const float* __restrict__ attn_r,
        unsigned short* __restrict__ hb, float* __restrict__ el,
        float* __restrict__ er, int N, int bg,
        const int* __restrict__ src, const int* __restrict__ dst,
        const int* __restrict__ offs, const int* __restrict__ ord,
        uint2* __restrict__ pair, int E) {
    const int t = threadIdx.x;
    if (blockIdx.x >= bg) {                // ---- scatter ----
        int e = (blockIdx.x - bg) * 256 + t;
        if (e < E) {
            int p = offs[dst[e]] + ord[e];
            pair[p] = make_uint2((unsigned)src[e], (unsigned)e);
        }
        return;
    }
    // ---- GEMM: each wave owns a 16-row x 256-col strip ----
    const int l = t & 63, wv = t >> 6;
    const int row0 = (blockIdx.x * 4 + wv) * 16;   // N % 16 == 0
    if (row0 >= N) return;
    const int m = l & 15, q = l >> 4;

    // preload all 8 A-fragments (row = row0+m), f32 -> bf16 in-register
    // (same f2b RNE as the old staged cvt -> bit-identical h)
    bf8 afr[8];
    const float* arow = feat + (size_t)(row0 + m) * HD + q * 8;
#pragma unroll
    for (int kc = 0; kc < 8; ++kc) {
        const float4 f0 = *(const float4*)(arow + kc * 32);
        const float4 f1 = *(const float4*)(arow + kc * 32 + 4);
        bf8 a;
        a[0] = (short)f2b(f0.x); a[1] = (short)f2b(f0.y);
        a[2] = (short)f2b(f0.z); a[3] = (short)f2b(f0.w);
        a[4] = (short)f2b(f1.x); a[5] = (short)f2b(f1.y);
        a[6] = (short)f2b(f1.z); a[7] = (short)f2b(f1.w);
        afr[kc] = a;
    }

    f4 acc[16];
#pragma unroll
    for (int nt = 0; nt < 16; ++nt) acc[nt] = (f4){0.f, 0.f, 0.f, 0.f};

    const unsigned short* bcol = Wtb + (size_t)m * HD + q * 8;   // col = nt*16+m
#pragma unroll
    for (int nt = 0; nt < 16; ++nt) {
        const unsigned short* bp = bcol + (size_t)nt * 16 * HD;
#pragma unroll
        for (int kc = 0; kc < 8; ++kc) {
            const bf8 b = *(const bf8*)(bp + kc * 32);
            acc[nt] = __builtin_amdgcn_mfma_f32_16x16x32_bf16(afr[kc], b, acc[nt], 0, 0, 0);
        }
    }

    // epilogue: C/D layout col = l&15, row = q*4+reg.  Store hb; full el/er
    // per row via width-16 butterflies.
#pragma unroll
    for (int h = 0; h < H; ++h) {
        float elp[4] = {0.f, 0.f, 0.f, 0.f};
        float erp[4] = {0.f, 0.f, 0.f, 0.f};
#pragma unroll
        for (int s = 0; s < 2; ++s) {
            const int nt = h * 2 + s;
            const int c = nt * 16 + m;
            const float alc = attn_l[c];
            const float arc = attn_r[c];
#pragma unroll
            for (int reg = 0; reg < 4; ++reg) {
                const float v = acc[nt][reg];
                hb[(size_t)(row0 + q * 4 + reg) * HD + c] = f2b(v);
                elp[reg] = fmaf(v, alc, elp[reg]);
                erp[reg] = fmaf(v, arc, erp[reg]);
            }
        }
#pragma unroll
        for (int reg = 0; reg < 4; ++reg) {
#pragma unroll
            for (int off = 1; off < 16; off <<= 1) {
                elp[reg] += __shfl_xor(elp[reg], off, 16);
                erp[reg] += __shfl_xor(erp[reg], off, 16);
            }
        }
        if (m == 0) {
#pragma unroll
            for (int reg = 0; reg < 4; ++reg) {
                el[(row0 + q * 4 + reg) * H + h] = elp[reg];
                er[(row0 + q * 4 + reg) * H + h] = erp[reg];
            }
        }
    }
}

// aggregation: ONE WAVE per node, zero LDS/barriers.  Dual-edge gather:
// lane = (half=lane>>5, sl=lane&31); each lane reads uint4 (8 cols, 16B), so
// one load instruction fetches TWO full 512B h-rows (half=0 -> edge j,
// half=1 -> edge j+1).  Halves merged at the end via shfl_xor(32).
__global__ __launch_bounds__(256) void k_node(
        const int* __restrict__ offs, const uint2* __restrict__ pair,
        const float* __restrict__ edge_emb, const float* __restrict__ el,
        const float* __restrict__ er, const float* __restrict__ M,
        const unsigned short* __restrict__ hb, const float* __restrict__ bias,
        float* __restrict__ out, int N) {
    const int t = threadIdx.x;
    const int lane = t & 63;
    const int v = blockIdx.x * 4 + (t >> 6);
    if (v >= N) return;
    const int hh = lane & 7;        // p-phase: head
    const int sl = lane & 31;       // col-chunk slot (8 cols = 16B)
    const int half = lane >> 5;     // edge parity
    const int cb = sl * 8;
    const int hq = sl >> 2;         // head of this chunk
    const int s0 = offs[v];
    const int deg = offs[v + 1] - s0;

    float Mreg[8];
#pragma unroll
    for (int k = 0; k < 8; ++k) Mreg[k] = M[k * 8 + hh];
    const float erv = er[(size_t)v * 8 + hh];
    const unsigned short* hbc = hb + cb;

    float a[8];
#pragma unroll
    for (int i = 0; i < 8; ++i) a[i] = 0.f;
    float psum = 0.f;

    for (int j0 = 0; j0 < deg; j0 += 64) {
        const int nj = min(64, deg - j0);
        uint2 prl = make_uint2(0u, 0u);
        if (lane < nj) prl = pair[s0 + j0 + lane];

        // ---- p-phase: 8 edges x 8 heads per sub-step (lane = jj*8+hh) ----
        float pv[8];
#pragma unroll
        for (int s = 0; s < 8; ++s) {
            pv[s] = 0.f;
            if (s * 8 < nj) {                       // wave-uniform
                const int j = s * 8 + (lane >> 3);
                const unsigned sx = __shfl(prl.x, j, 64);
                const unsigned ex = __shfl(prl.y, j, 64);
                const float eev = edge_emb[(size_t)ex * 8 + hh];
                float lg = el[(size_t)sx * 8 + hh] + erv;
#pragma unroll
                for (int k = 0; k < 8; ++k)
                    lg = fmaf(__shfl(eev, k, 8), Mreg[k], lg);
                lg = (lg >= 0.f) ? lg : NEG_SLOPE * lg;
                if (j < nj) { pv[s] = __expf(lg); psum += pv[s]; }
            }
        }

        // ---- aggregation: 2 edges per load instruction ----
#pragma unroll
        for (int s = 0; s < 8; ++s) {
            if (s * 8 >= nj) break;                 // wave-uniform
#pragma unroll
            for (int u = 0; u < 4; ++u) {
                if (s * 8 + 2 * u >= nj) break;     // wave-uniform
                const int jj = 2 * u + half;
                const unsigned sx = __shfl(prl.x, s * 8 + jj, 64);
                const float pj = __shfl(pv[s], jj * 8 + hq, 64);  // 0 if j>=nj
                const uint4 w = *(const uint4*)(hbc + (size_t)sx * HD);
                a[0] = fmaf(pj, __uint_as_float(w.x << 16), a[0]);
                a[1] = fmaf(pj, __uint_as_float(w.x & 0xffff0000u), a[1]);
                a[2] = fmaf(pj, __uint_as_float(w.y << 16), a[2]);
                a[3] = fmaf(pj, __uint_as_float(w.y & 0xffff0000u), a[3]);
                a[4] = fmaf(pj, __uint_as_float(w.z << 16), a[4]);
                a[5] = fmaf(pj, __uint_as_float(w.z & 0xffff0000u), a[5]);
                a[6] = fmaf(pj, __uint_as_float(w.w << 16), a[6]);
                a[7] = fmaf(pj, __uint_as_float(w.w & 0xffff0000u), a[7]);
            }
        }
    }

    // merge edge-parity halves (same cols, disjoint edge subsets)
#pragma unroll
    for (int i = 0; i < 8; ++i) a[i] += __shfl_xor(a[i], 32, 64);

    // per-head sum of p, deferred normalization
    psum += __shfl_xor(psum, 8, 64);
    psum += __shfl_xor(psum, 16, 64);
    psum += __shfl_xor(psum, 32, 64);
    const float rs = 1.f / (__shfl(psum, hq, 8) + 1e-9f);
    if (half == 0) {
        const float4 b0 = *(const float4*)&bias[cb];
        const float4 b1 = *(const float4*)&bias[cb + 4];
        *(float4*)&out[(size_t)v * HD + cb] =
            make_float4(fmaf(a[0], rs, b0.x), fmaf(a[1], rs, b0.y),
                        fmaf(a[2], rs, b0.z), fmaf(a[3], rs, b0.w));
        *(float4*)&out[(size_t)v * HD + cb + 4] =
            make_float4(fmaf(a[4], rs, b1.x), fmaf(a[5], rs, b1.y),
                        fmaf(a[6], rs, b1.z), fmaf(a[7], rs, b1.w));
    }
}

extern "C" void kernel_launch(void* const* d_in, const int* in_sizes, int n_in,
                              void* d_out, int out_size, void* d_ws, size_t ws_size,
                              hipStream_t stream) {
    const float* feat     = (const float*)d_in[0];
    const float* edge_emb = (const float*)d_in[1];
    const int*   src      = (const int*)d_in[2];
    const int*   dst      = (const int*)d_in[3];
    const float* W_src    = (const float*)d_in[4];
    const float* W_e      = (const float*)d_in[5];
    const float* attn_l   = (const float*)d_in[6];
    const float* attn_r   = (const float*)d_in[7];
    const float* attn_e   = (const float*)d_in[8];
    const float* bias     = (const float*)d_in[9];
    float* out = (float*)d_out;

    const int N = in_sizes[0] / HD;
    const int E = in_sizes[2];

    char* ws = (char*)d_ws;
    unsigned short* hb = (unsigned short*)ws; ws += (size_t)N * HD * 2;   // bf16 h
    uint2* pair = (uint2*)ws; ws += (size_t)E * 8;
    float* el   = (float*)ws; ws += (size_t)N * H * 4;
    float* er   = (float*)ws; ws += (size_t)N * H * 4;
    int*   cnt  = (int*)ws;   ws += (size_t)N * 4;
    int* offs   = (int*)ws; ws += (size_t)(N + 1) * 4;
    int* ord    = (int*)ws; ws += (size_t)E * 4;
    unsigned short* Wtb = (unsigned short*)ws; ws += (size_t)HD * HD * 2;
    int* btot  = (int*)ws; ws += 64 * 4;
    float* M   = (float*)ws; ws += 256;

    const int bh  = (E + 255) / 256;
    const int nsb = (N + SCB - 1) / SCB;   // <= 64
    const int bg  = ((N + 15) / 16 + 3) / 4;   // gemm blocks (4 waves each)
    const int bs  = (E + 255) / 256;           // scatter blocks

    hipMemsetAsync(cnt, 0, (size_t)N * 4, stream);
    k_prep  <<<HD + bh + 1, 256, 0, stream>>>(W_src, Wtb, W_e, attn_e, M,
                                              dst, cnt, ord, E, bh);
    k_scan1 <<<nsb, SCB, 0, stream>>>(cnt, offs, btot, N);
    k_scan3 <<<nsb, SCB, 0, stream>>>(offs, btot, N, E, nsb);
    k_fuse  <<<bg + bs, 256, 0, stream>>>(feat, Wtb, attn_l, attn_r, hb, el, er,
                                          N, bg, src, dst, offs, ord, pair, E);
    k_node  <<<(N + 3) / 4, 256, 0, stream>>>(offs, pair, edge_emb, el, er, M,
                                              hb, bias, out, N);
}

// Round 6
// 296.631 us; speedup vs baseline: 1.4769x; 1.1290x over previous
//
#include <hip/hip_runtime.h>

#define H 8
#define D 32
#define HD 256
#define NEG_SLOPE 0.2f
#define SCB 1024

typedef __attribute__((ext_vector_type(8))) short bf8;
typedef __attribute__((ext_vector_type(4))) float f4;

// fp32 -> bf16 (round-to-nearest-even), integer path
__device__ __forceinline__ unsigned short f2b(float x) {
    unsigned u = __float_as_uint(x);
    unsigned r = (u + 0x7fffu + ((u >> 16) & 1u)) >> 16;
    return (unsigned short)r;
}

// prep: W transpose->bf16 | dst histogram (+per-edge ordinal) | M_e (8x8)
__global__ __launch_bounds__(256) void k_prep(
        const float* __restrict__ W, unsigned short* __restrict__ Wtb,
        const float* __restrict__ W_e, const float* __restrict__ attn_e,
        float* __restrict__ M, const int* __restrict__ dst, int* __restrict__ cnt,
        int* __restrict__ ord, int E, int bh) {
    const int b = blockIdx.x, t = threadIdx.x;
    if (b < HD) {                          // ---- W transpose ----
        Wtb[b * HD + t] = f2b(W[t * HD + b]);
    } else if (b < HD + bh) {              // ---- histogram + ordinal ----
        int e = (b - HD) * 256 + t;
        if (e < E) ord[e] = atomicAdd(&cnt[dst[e]], 1);
    } else {                               // ---- M_e ----
        if (t < 64) {
            int k = t >> 3, hh = t & 7;
            float acc = 0.f;
            for (int d = 0; d < D; ++d)
                acc = fmaf(W_e[k * HD + hh * D + d], attn_e[hh * D + d], acc);
            M[k * 8 + hh] = acc;
        }
    }
}

// parallel exclusive scan, step 1: block-local scan + block totals
__global__ __launch_bounds__(1024) void k_scan1(const int* __restrict__ cnt,
                                                int* __restrict__ offs,
                                                int* __restrict__ btot, int N) {
    __shared__ int wtot[16], wbase[16];
    const int t = threadIdx.x, wid = t >> 6, lane = t & 63;
    int i = blockIdx.x * SCB + t;
    int v = (i < N) ? cnt[i] : 0;
    int x = v;
#pragma unroll
    for (int off = 1; off < 64; off <<= 1) {
        int y = __shfl_up(x, off, 64);
        if (lane >= off) x += y;
    }
    if (lane == 63) wtot[wid] = x;
    __syncthreads();
    if (t < 16) {
        int w = wtot[t], xs = w;
#pragma unroll
        for (int off = 1; off < 16; off <<= 1) {
            int y = __shfl_up(xs, off, 64);
            if (t >= off) xs += y;
        }
        wbase[t] = xs - w;
        if (t == 15) btot[blockIdx.x] = xs;
    }
    __syncthreads();
    if (i < N) offs[i] = wbase[wid] + (x - v);
}

// step 2 (fused scan2+scan3): wave 0 re-scans the <=64 block totals, then the
// whole block adds its base.
__global__ __launch_bounds__(1024) void k_scan3(int* __restrict__ offs,
                                                const int* __restrict__ btot,
                                                int N, int E, int nb) {
    __shared__ int bb;
    const int t = threadIdx.x;
    if (t < 64) {
        int vv = (t < nb) ? btot[t] : 0;
        int x = vv;
#pragma unroll
        for (int off = 1; off < 64; off <<= 1) {
            int y = __shfl_up(x, off, 64);
            if (t >= off) x += y;
        }
        if (t == blockIdx.x) bb = x - vv;   // exclusive base for this block
    }
    __syncthreads();
    const int i = blockIdx.x * SCB + t;
    if (i < N) offs[i] += bb;
    if (i == 0) offs[N] = E;
}

// fused dispatch, 512 threads:
//  [0,bg)    : MFMA GEMM, 8 waves x 16 rows.  Wt staged into LDS in two 64KB
//              halves with bank-swizzle (byte ^= (row&7)*16) so ds_read_b128
//              B-fragments are conflict-free; f32 A cvt'd in-register.
//  [bg,bg+bs): atomic-free CSR scatter, 4 edges/thread (ILP).
__global__ __launch_bounds__(512) void k_fuse(
        const float* __restrict__ feat, const unsigned short* __restrict__ Wtb,
        const float* __restrict__ attn_l, const float* __restrict__ attn_r,
        unsigned short* __restrict__ hb, float* __restrict__ el,
        float* __restrict__ er, int N, int bg,
        const int* __restrict__ src, const int* __restrict__ dst,
        const int* __restrict__ offs, const int* __restrict__ ord,
        uint2* __restrict__ pair, int E) {
    const int t = threadIdx.x;
    if (blockIdx.x >= bg) {                // ---- scatter ----
        const int base = (blockIdx.x - bg) * 2048;
        const int end = min(base + 2048, E);
        for (int e = base + t; e < end; e += 512) {
            int p = offs[dst[e]] + ord[e];
            pair[p] = make_uint2((unsigned)src[e], (unsigned)e);
        }
        return;
    }
    __shared__ unsigned short lwt[128 * HD];   // 64 KB: half of Wt, swizzled
    const int l = t & 63, wv = t >> 6;
    const int row0 = (blockIdx.x * 8 + wv) * 16;
    const bool act = row0 < N;             // tail waves stage+barrier only
    const int m = l & 15, q = l >> 4;

    // preload all 8 A-fragments (row = row0+m), f32 -> bf16 in-register;
    // issued before staging so HBM latency hides under the LDS fill.
    bf8 afr[8];
    if (act) {
        const float* arow = feat + (size_t)(row0 + m) * HD + q * 8;
#pragma unroll
        for (int kc = 0; kc < 8; ++kc) {
            const float4 f0 = *(const float4*)(arow + kc * 32);
            const float4 f1 = *(const float4*)(arow + kc * 32 + 4);
            bf8 a;
            a[0] = (short)f2b(f0.x); a[1] = (short)f2b(f0.y);
            a[2] = (short)f2b(f0.z); a[3] = (short)f2b(f0.w);
            a[4] = (short)f2b(f1.x); a[5] = (short)f2b(f1.y);
            a[6] = (short)f2b(f1.z); a[7] = (short)f2b(f1.w);
            afr[kc] = a;
        }
    }

    f4 acc[16];
#pragma unroll
    for (int nt = 0; nt < 16; ++nt) acc[nt] = (f4){0.f, 0.f, 0.f, 0.f};

    const uint4* wt4 = (const uint4*)Wtb;
    uint4* l4 = (uint4*)lwt;
#pragma unroll
    for (int half = 0; half < 2; ++half) {
        if (half) __syncthreads();         // all waves done reading half 0
        // stage 64KB chunk: dest uint4 index u ^ (row&7)  (row = u>>5)
#pragma unroll
        for (int i = 0; i < 8; ++i) {
            const int u = i * 512 + t;
            l4[u ^ ((u >> 5) & 7)] = wt4[half * 4096 + u];
        }
        __syncthreads();
        if (act) {
#pragma unroll
            for (int ntl = 0; ntl < 8; ++ntl) {
                const int nt = half * 8 + ntl;
                const int lc = ntl * 16 + m;          // chunk-local Wt row
                const unsigned short* bp = lwt + lc * HD;
                const int sw = (lc & 7) * 8;          // swizzle, ushort units
#pragma unroll
                for (int kc = 0; kc < 8; ++kc) {
                    const bf8 b = *(const bf8*)(bp + ((q * 8 + kc * 32) ^ sw));
                    acc[nt] = __builtin_amdgcn_mfma_f32_16x16x32_bf16(
                                  afr[kc], b, acc[nt], 0, 0, 0);
                }
            }
        }
    }
    if (!act) return;

    // epilogue: C/D layout col = l&15, row = q*4+reg.  Store hb; full el/er
    // per row via width-16 butterflies.
#pragma unroll
    for (int h = 0; h < H; ++h) {
        float elp[4] = {0.f, 0.f, 0.f, 0.f};
        float erp[4] = {0.f, 0.f, 0.f, 0.f};
#pragma unroll
        for (int s = 0; s < 2; ++s) {
            const int nt = h * 2 + s;
            const int c = nt * 16 + m;
            const float alc = attn_l[c];
            const float arc = attn_r[c];
#pragma unroll
            for (int reg = 0; reg < 4; ++reg) {
                const float v = acc[nt][reg];
                hb[(size_t)(row0 + q * 4 + reg) * HD + c] = f2b(v);
                elp[reg] = fmaf(v, alc, elp[reg]);
                erp[reg] = fmaf(v, arc, erp[reg]);
            }
        }
#pragma unroll
        for (int reg = 0; reg < 4; ++reg) {
#pragma unroll
            for (int off = 1; off < 16; off <<= 1) {
                elp[reg] += __shfl_xor(elp[reg], off, 16);
                erp[reg] += __shfl_xor(erp[reg], off, 16);
            }
        }
        if (m == 0) {
#pragma unroll
            for (int reg = 0; reg < 4; ++reg) {
                el[(row0 + q * 4 + reg) * H + h] = elp[reg];
                er[(row0 + q * 4 + reg) * H + h] = erp[reg];
            }
        }
    }
}

// aggregation: ONE WAVE per node, zero LDS/barriers.  Dual-edge gather:
// lane = (half=lane>>5, sl=lane&31); each lane reads uint4 (8 cols, 16B), so
// one load instruction fetches TWO full 512B h-rows.  Halves merged at the
// end via shfl_xor(32).
__global__ __launch_bounds__(256) void k_node(
        const int* __restrict__ offs, const uint2* __restrict__ pair,
        const float* __restrict__ edge_emb, const float* __restrict__ el,
        const float* __restrict__ er, const float* __restrict__ M,
        const unsigned short* __restrict__ hb, const float* __restrict__ bias,
        float* __restrict__ out, int N) {
    const int t = threadIdx.x;
    const int lane = t & 63;
    const int v = blockIdx.x * 4 + (t >> 6);
    if (v >= N) return;
    const int hh = lane & 7;        // p-phase: head
    const int sl = lane & 31;       // col-chunk slot (8 cols = 16B)
    const int half = lane >> 5;     // edge parity
    const int cb = sl * 8;
    const int hq = sl >> 2;         // head of this chunk
    const int s0 = offs[v];
    const int deg = offs[v + 1] - s0;

    float Mreg[8];
#pragma unroll
    for (int k = 0; k < 8; ++k) Mreg[k] = M[k * 8 + hh];
    const float erv = er[(size_t)v * 8 + hh];
    const unsigned short* hbc = hb + cb;

    float a[8];
#pragma unroll
    for (int i = 0; i < 8; ++i) a[i] = 0.f;
    float psum = 0.f;

    for (int j0 = 0; j0 < deg; j0 += 64) {
        const int nj = min(64, deg - j0);
        uint2 prl = make_uint2(0u, 0u);
        if (lane < nj) prl = pair[s0 + j0 + lane];

        // ---- p-phase: 8 edges x 8 heads per sub-step (lane = jj*8+hh) ----
        float pv[8];
#pragma unroll
        for (int s = 0; s < 8; ++s) {
            pv[s] = 0.f;
            if (s * 8 < nj) {                       // wave-uniform
                const int j = s * 8 + (lane >> 3);
                const unsigned sx = __shfl(prl.x, j, 64);
                const unsigned ex = __shfl(prl.y, j, 64);
                const float eev = edge_emb[(size_t)ex * 8 + hh];
                float lg = el[(size_t)sx * 8 + hh] + erv;
#pragma unroll
                for (int k = 0; k < 8; ++k)
                    lg = fmaf(__shfl(eev, k, 8), Mreg[k], lg);
                lg = (lg >= 0.f) ? lg : NEG_SLOPE * lg;
                if (j < nj) { pv[s] = __expf(lg); psum += pv[s]; }
            }
        }

        // ---- aggregation: 2 edges per load instruction ----
#pragma unroll
        for (int s = 0; s < 8; ++s) {
            if (s * 8 >= nj) break;                 // wave-uniform
#pragma unroll
            for (int u = 0; u < 4; ++u) {
                if (s * 8 + 2 * u >= nj) break;     // wave-uniform
                const int jj = 2 * u + half;
                const unsigned sx = __shfl(prl.x, s * 8 + jj, 64);
                const float pj = __shfl(pv[s], jj * 8 + hq, 64);  // 0 if j>=nj
                const uint4 w = *(const uint4*)(hbc + (size_t)sx * HD);
                a[0] = fmaf(pj, __uint_as_float(w.x << 16), a[0]);
                a[1] = fmaf(pj, __uint_as_float(w.x & 0xffff0000u), a[1]);
                a[2] = fmaf(pj, __uint_as_float(w.y << 16), a[2]);
                a[3] = fmaf(pj, __uint_as_float(w.y & 0xffff0000u), a[3]);
                a[4] = fmaf(pj, __uint_as_float(w.z << 16), a[4]);
                a[5] = fmaf(pj, __uint_as_float(w.z & 0xffff0000u), a[5]);
                a[6] = fmaf(pj, __uint_as_float(w.w << 16), a[6]);
                a[7] = fmaf(pj, __uint_as_float(w.w & 0xffff0000u), a[7]);
            }
        }
    }

    // merge edge-parity halves (same cols, disjoint edge subsets)
#pragma unroll
    for (int i = 0; i < 8; ++i) a[i] += __shfl_xor(a[i], 32, 64);

    // per-head sum of p, deferred normalization
    psum += __shfl_xor(psum, 8, 64);
    psum += __shfl_xor(psum, 16, 64);
    psum += __shfl_xor(psum, 32, 64);
    const float rs = 1.f / (__shfl(psum, hq, 8) + 1e-9f);
    if (half == 0) {
        const float4 b0 = *(const float4*)&bias[cb];
        const float4 b1 = *(const float4*)&bias[cb + 4];
        *(float4*)&out[(size_t)v * HD + cb] =
            make_float4(fmaf(a[0], rs, b0.x), fmaf(a[1], rs, b0.y),
                        fmaf(a[2], rs, b0.z), fmaf(a[3], rs, b0.w));
        *(float4*)&out[(size_t)v * HD + cb + 4] =
            make_float4(fmaf(a[4], rs, b1.x), fmaf(a[5], rs, b1.y),
                        fmaf(a[6], rs, b1.z), fmaf(a[7], rs, b1.w));
    }
}

extern "C" void kernel_launch(void* const* d_in, const int* in_sizes, int n_in,
                              void* d_out, int out_size, void* d_ws, size_t ws_size,
                              hipStream_t stream) {
    const float* feat     = (const float*)d_in[0];
    const float* edge_emb = (const float*)d_in[1];
    const int*   src      = (const int*)d_in[2];
    const int*   dst      = (const int*)d_in[3];
    const float* W_src    = (const float*)d_in[4];
    const float* W_e      = (const float*)d_in[5];
    const float* attn_l   = (const float*)d_in[6];
    const float* attn_r   = (const float*)d_in[7];
    const float* attn_e   = (const float*)d_in[8];
    const float* bias     = (const float*)d_in[9];
    float* out = (float*)d_out;

    const int N = in_sizes[0] / HD;
    const int E = in_sizes[2];

    char* ws = (char*)d_ws;
    unsigned short* hb = (unsigned short*)ws; ws += (size_t)N * HD * 2;   // bf16 h
    uint2* pair = (uint2*)ws; ws += (size_t)E * 8;
    float* el   = (float*)ws; ws += (size_t)N * H * 4;
    float* er   = (float*)ws; ws += (size_t)N * H * 4;
    int*   cnt  = (int*)ws;   ws += (size_t)N * 4;
    int* offs   = (int*)ws; ws += (size_t)(N + 1) * 4;
    int* ord    = (int*)ws; ws += (size_t)E * 4;
    unsigned short* Wtb = (unsigned short*)ws; ws += (size_t)HD * HD * 2;
    int* btot  = (int*)ws; ws += 64 * 4;
    float* M   = (float*)ws; ws += 256;

    const int bh  = (E + 255) / 256;
    const int nsb = (N + SCB - 1) / SCB;   // <= 64
    const int bg  = ((N + 15) / 16 + 7) / 8;   // gemm blocks (8 waves each)
    const int bs  = (E + 2047) / 2048;         // scatter blocks (ILP-4)

    hipMemsetAsync(cnt, 0, (size_t)N * 4, stream);
    k_prep  <<<HD + bh + 1, 256, 0, stream>>>(W_src, Wtb, W_e, attn_e, M,
                                              dst, cnt, ord, E, bh);
    k_scan1 <<<nsb, SCB, 0, stream>>>(cnt, offs, btot, N);
    k_scan3 <<<nsb, SCB, 0, stream>>>(offs, btot, N, E, nsb);
    k_fuse  <<<bg + bs, 512, 0, stream>>>(feat, Wtb, attn_l, attn_r, hb, el, er,
                                          N, bg, src, dst, offs, ord, pair, E);
    k_node  <<<(N + 3) / 4, 256, 0, stream>>>(offs, pair, edge_emb, el, er, M,
                                              hb, bias, out, N);
}